// Round 7
// baseline (160.605 us; speedup 1.0000x reference)
//
#include <hip/hip_runtime.h>

typedef __attribute__((ext_vector_type(4))) float f32x4;
typedef __attribute__((ext_vector_type(8))) short bf16x8;

#define D_MODEL 1024
#define NQK     2048
#define LSEQ    2048
#define NB      4
#define NX4     2097152   // 8192*1024/4
#define NW4     524288    // 2048*1024/4

__device__ inline unsigned short f2bf(float f) {
  unsigned u = __float_as_uint(f);
  unsigned r = (u + 0x7FFFu + ((u >> 16) & 1u)) >> 16;
  return (unsigned short)r;
}

__device__ inline void gl_lds16(const void* g, void* l) {
  __builtin_amdgcn_global_load_lds((const __attribute__((address_space(1))) void*)g,
                                   (__attribute__((address_space(3))) void*)l, 16, 0, 0);
}

// ---------------- fp32 -> bf16 convert (X then W) + colsum zeroing ----------------
__global__ __launch_bounds__(256) void cvt_zero_kernel(
    const float4* __restrict__ X, const float4* __restrict__ W,
    ushort4* __restrict__ dst, float* __restrict__ colsum) {
  int i = blockIdx.x * 256 + threadIdx.x;
  if (blockIdx.x < 32) colsum[i] = 0.f;          // zero colsum[8192]
  float4 v = (i < NX4) ? X[i] : W[i - NX4];
  ushort4 o;
  o.x = f2bf(v.x); o.y = f2bf(v.y); o.z = f2bf(v.z); o.w = f2bf(v.w);
  dst[i] = o;
}

// ---------------- GEMM: Q,K = X W^T + bias, stored as fp8 e4m3 (unscaled) ----------------
__global__ __launch_bounds__(256) void gemm_qk(
    const unsigned short* __restrict__ Xb,   // [8192][1024] bf16
    const unsigned short* __restrict__ Wb,   // [2048][1024] bf16
    const float* __restrict__ bias,          // [3072]
    unsigned char* __restrict__ C)           // [8192][2048] fp8 e4m3
{
  __shared__ unsigned short As[128 * 32];  // 8KB
  __shared__ unsigned short Bs[128 * 32];  // 8KB
  int t = threadIdx.x;
  int w = t >> 6, lane = t & 63;
  int l15 = lane & 15, lg = lane >> 4;
  int bid = blockIdx.x;
  int k2 = bid >> 3, xcd = bid & 7;
  int m0 = (xcd * 8 + (k2 >> 4)) * 128;
  int n0 = (k2 & 15) * 128;
  int wm = (w >> 1) * 64, wn = (w & 1) * 64;
  f32x4 acc[4][4] = {};

  for (int kt = 0; kt < D_MODEL / 32; ++kt) {
#pragma unroll
    for (int i = 0; i < 2; ++i) {
      int ob = w * 1024 + i * 4096;
      int o = ob + lane * 16;
      int row = o >> 6;
      int kb = (o & 63) ^ (((row >> 1) & 3) << 4);
      gl_lds16(Xb + (m0 + row) * D_MODEL + kt * 32 + (kb >> 1), (char*)As + ob);
      gl_lds16(Wb + (n0 + row) * D_MODEL + kt * 32 + (kb >> 1), (char*)Bs + ob);
    }
    __syncthreads();
    bf16x8 a[4], b[4];
#pragma unroll
    for (int mi = 0; mi < 4; mi++) {
      int row = wm + mi * 16 + l15;
      int kb = (lg * 16) ^ (((row >> 1) & 3) << 4);
      a[mi] = *(const bf16x8*)((const char*)As + row * 64 + kb);
    }
#pragma unroll
    for (int ni = 0; ni < 4; ni++) {
      int row = wn + ni * 16 + l15;
      int kb = (lg * 16) ^ (((row >> 1) & 3) << 4);
      b[ni] = *(const bf16x8*)((const char*)Bs + row * 64 + kb);
    }
#pragma unroll
    for (int mi = 0; mi < 4; mi++)
#pragma unroll
      for (int ni = 0; ni < 4; ni++)
        acc[mi][ni] = __builtin_amdgcn_mfma_f32_16x16x32_bf16(a[mi], b[ni], acc[mi][ni], 0, 0, 0);
    __syncthreads();
  }

#pragma unroll
  for (int ni = 0; ni < 4; ni++) {
    int n = n0 + wn + ni * 16 + l15;
    float bv = bias[n];
#pragma unroll
    for (int mi = 0; mi < 4; mi++) {
      int mbase = m0 + wm + mi * 16 + lg * 4;
#pragma unroll
      for (int r = 0; r < 4; r++) {
        float v = acc[mi][ni][r] + bv;
        unsigned u = __builtin_amdgcn_cvt_pk_fp8_f32(v, v, 0, false);
        C[(size_t)(mbase + r) * NQK + n] = (unsigned char)u;
      }
    }
  }
}

// ---------------- fused attention column sums (fp8, 16 waves, shared K strips) ----------------
// wg = 1024 threads (16 waves = 2m x 8n). wg covers 64 q-rows x all 2048 keys of one (b,h).
// Strip wn (256 keys) is staged 16-keys-at-a-time into a shared double-buffered 2x4KB LDS
// slice by its two m-partner waves. Raw barriers + counted vmcnt(2) keep loads in flight.
// waves_per_eu pinned to (4,4): 1 block/CU, 128-VGPR budget -> NO scratch spill (round-6 bug).
__global__ __attribute__((amdgpu_flat_work_group_size(1024, 1024),
                          amdgpu_waves_per_eu(4, 4))) void attn_fused(
    const unsigned char* __restrict__ C,   // [8192][2048] fp8
    float* __restrict__ colsum)            // [4][2048]
{
  __shared__ unsigned char Ks[65536];      // 8 strips x 2 bufs x 4KB
  int t = threadIdx.x;
  int w = t >> 6, lane = t & 63;
  int wm = w >> 3, wn = w & 7;
  int l15 = lane & 15, lg = lane >> 4;

  // XCD swizzle: 64 consecutive nids (2 bh) per XCD -> K slice (1MB fp8) L2-resident
  int nid = (blockIdx.x & 7) * 64 + (blockIdx.x >> 3);
  int bh = nid >> 5, qblk = nid & 31;
  int b = bh >> 2, h = bh & 3;

  const unsigned char* Qbase = C + (size_t)(b * LSEQ + qblk * 64 + wm * 32) * NQK + h * 256;
  const unsigned char* Kbase = C + (size_t)(b * LSEQ) * NQK + 1024 + h * 256;
  unsigned char* strip = Ks + wn * 8192;

  // Q fragments: 32 rows x 256 hd fp8 (A-operand layout), 32 VGPRs
  long qf[2][8];
#pragma unroll
  for (int mi = 0; mi < 2; mi++)
#pragma unroll
    for (int kk = 0; kk < 8; kk++)
      qf[mi][kk] = *(const long*)(Qbase + (size_t)(mi * 16 + l15) * NQK + kk * 32 + lg * 8);
  asm volatile("s_waitcnt vmcnt(0)" ::: "memory");   // drain Q so vmcnt counts are exact
  __builtin_amdgcn_sched_barrier(0);

  float zacc[2][4] = {};
  unsigned E[16][2];                       // exp(S) packed 4x e4m3 per u32
  int swz = (l15 & 7) << 4;

  // wave stages its half (8 keys) of strip wn's 16-key tile: 2 x gl_lds16
#define STAGE(nn, bi)                                                          \
  {                                                                            \
    _Pragma("unroll")                                                          \
    for (int j = 0; j < 2; j++) {                                              \
      int i = wm * 2 + j;                                                      \
      int o = i * 1024 + lane * 16;                                            \
      int s = o >> 8;                                                          \
      int db = (o & 255) ^ ((s & 7) << 4);                                     \
      gl_lds16(Kbase + (size_t)(wn * 256 + (nn) * 16 + s) * NQK + db,          \
               strip + (bi) * 4096 + o);                                       \
    }                                                                          \
  }

  STAGE(0, 0);

#pragma unroll
  for (int n = 0; n < 16; n++) {
    int bi = n & 1;
    __builtin_amdgcn_sched_barrier(0);
    __builtin_amdgcn_s_barrier();                    // B1: all done computing tile n-1
    if (n < 15) {
      STAGE(n + 1, bi ^ 1);
      asm volatile("s_waitcnt vmcnt(2)" ::: "memory"); // my tile-n loads landed, n+1 in flight
    } else {
      asm volatile("s_waitcnt vmcnt(0)" ::: "memory");
    }
    __builtin_amdgcn_sched_barrier(0);
    __builtin_amdgcn_s_barrier();                    // B2: tile n fully in LDS
    __builtin_amdgcn_sched_barrier(0);

    const unsigned char* bufp = strip + bi * 4096;
    f32x4 acc0 = {}, acc1 = {};
#pragma unroll
    for (int kk = 0; kk < 8; kk++) {
      long kf = *(const long*)(bufp + l15 * 256 + ((kk * 32 + lg * 8) ^ swz));
      acc0 = __builtin_amdgcn_mfma_f32_16x16x32_fp8_fp8(qf[0][kk], kf, acc0, 0, 0, 0);
      acc1 = __builtin_amdgcn_mfma_f32_16x16x32_fp8_fp8(qf[1][kk], kf, acc1, 0, 0, 0);
    }
    {
      float e0 = __expf(acc0[0] * 0.0625f), e1 = __expf(acc0[1] * 0.0625f);
      float e2 = __expf(acc0[2] * 0.0625f), e3 = __expf(acc0[3] * 0.0625f);
      zacc[0][0] += e0; zacc[0][1] += e1; zacc[0][2] += e2; zacc[0][3] += e3;
      unsigned u = __builtin_amdgcn_cvt_pk_fp8_f32(e0, e1, 0, false);
      E[n][0] = __builtin_amdgcn_cvt_pk_fp8_f32(e2, e3, (int)u, true);
    }
    {
      float e0 = __expf(acc1[0] * 0.0625f), e1 = __expf(acc1[1] * 0.0625f);
      float e2 = __expf(acc1[2] * 0.0625f), e3 = __expf(acc1[3] * 0.0625f);
      zacc[1][0] += e0; zacc[1][1] += e1; zacc[1][2] += e2; zacc[1][3] += e3;
      unsigned u = __builtin_amdgcn_cvt_pk_fp8_f32(e0, e1, 0, false);
      E[n][1] = __builtin_amdgcn_cvt_pk_fp8_f32(e2, e3, (int)u, true);
    }
  }
#undef STAGE

  // ---- Z combine across the 8 key-strip waves of each m-half ----
  __syncthreads();
  float* Zpf = (float*)Ks;                 // [16][32]
#pragma unroll
  for (int mi = 0; mi < 2; mi++)
#pragma unroll
    for (int r = 0; r < 4; r++) {
      float z = zacc[mi][r];
      z += __shfl_xor(z, 1, 64);
      z += __shfl_xor(z, 2, 64);
      z += __shfl_xor(z, 4, 64);
      z += __shfl_xor(z, 8, 64);
      if (l15 == 0) Zpf[w * 32 + mi * 16 + lg * 4 + r] = z;
    }
  __syncthreads();

  float invz[2][4];
#pragma unroll
  for (int mi = 0; mi < 2; mi++) {
    f32x4 s = {};
#pragma unroll
    for (int j = 0; j < 8; j++) {
      f32x4 p = *(const f32x4*)(Zpf + (wm * 8 + j) * 32 + mi * 16 + lg * 4);
      s += p;
    }
    invz[mi][0] = 1.0f / s[0]; invz[mi][1] = 1.0f / s[1];
    invz[mi][2] = 1.0f / s[2]; invz[mi][3] = 1.0f / s[3];
  }

  // ---- column sums straight from register-resident fp8 E ----
#pragma unroll
  for (int n = 0; n < 16; n++) {
    float c = 0.f;
#pragma unroll
    for (int mi = 0; mi < 2; mi++) {
      c += __builtin_amdgcn_cvt_f32_fp8(E[n][mi], 0) * invz[mi][0];
      c += __builtin_amdgcn_cvt_f32_fp8(E[n][mi], 1) * invz[mi][1];
      c += __builtin_amdgcn_cvt_f32_fp8(E[n][mi], 2) * invz[mi][2];
      c += __builtin_amdgcn_cvt_f32_fp8(E[n][mi], 3) * invz[mi][3];
    }
    c += __shfl_xor(c, 16, 64);
    c += __shfl_xor(c, 32, 64);
    if (lane < 16)
      atomicAdd(&colsum[b * LSEQ + wn * 256 + n * 16 + l15], c);
  }
}

// ---------------- finalize ----------------
__global__ __launch_bounds__(256) void finalize_kernel(
    const float* __restrict__ colsum, float* __restrict__ out) {
  __shared__ float red[256];
  int t = threadIdx.x;
  float acc = 0.f;
  for (int i = t; i < NB * LSEQ; i += 256) {
    float aw = colsum[i] * (1.0f / 8192.0f) + 1e-8f;
    acc += -aw * __logf(aw);
  }
  red[t] = acc;
  __syncthreads();
  for (int s = 128; s > 0; s >>= 1) {
    if (t < s) red[t] += red[t + s];
    __syncthreads();
  }
  if (t == 0) {
    float me = red[0] * 0.25f;
    out[0] = 1.0f / (1.0f + __expf(-me));
  }
}

extern "C" void kernel_launch(void* const* d_in, const int* in_sizes, int n_in,
                              void* d_out, int out_size, void* d_ws, size_t ws_size,
                              hipStream_t stream) {
  const float* hs   = (const float*)d_in[0];   // [4,2048,1024]
  const float* wgt  = (const float*)d_in[1];   // [3072,1024]
  const float* bias = (const float*)d_in[2];   // [3072]
  float* out = (float*)d_out;
  char* ws = (char*)d_ws;

  unsigned short* Xb = (unsigned short*)(ws);                   // 16 MB
  unsigned short* Wb = (unsigned short*)(ws + (16u << 20));     // 4 MB
  unsigned char*  C8 = (unsigned char*)(ws + (20u << 20));      // 16 MB fp8
  float* colsum = (float*)(ws + (36u << 20));                   // 32 KB

  cvt_zero_kernel<<<(NX4 + NW4) / 256, 256, 0, stream>>>(
      (const float4*)hs, (const float4*)wgt, (ushort4*)Xb, colsum);

  gemm_qk<<<1024, 256, 0, stream>>>(Xb, Wb, bias, C8);

  attn_fused<<<512, 1024, 0, stream>>>(C8, colsum);
  finalize_kernel<<<1, 256, 0, stream>>>(colsum, out);
}

// Round 8
// 156.538 us; speedup vs baseline: 1.0260x; 1.0260x over previous
//
#include <hip/hip_runtime.h>

typedef __attribute__((ext_vector_type(4))) float f32x4;
typedef __attribute__((ext_vector_type(8))) short bf16x8;

#define D_MODEL 1024
#define NQK     2048
#define LSEQ    2048
#define NB      4
#define NX4     2097152   // 8192*1024/4
#define NW4     524288    // 2048*1024/4

__device__ inline unsigned short f2bf(float f) {
  unsigned u = __float_as_uint(f);
  unsigned r = (u + 0x7FFFu + ((u >> 16) & 1u)) >> 16;
  return (unsigned short)r;
}

__device__ inline void gl_lds16(const void* g, void* l) {
  __builtin_amdgcn_global_load_lds((const __attribute__((address_space(1))) void*)g,
                                   (__attribute__((address_space(3))) void*)l, 16, 0, 0);
}

// ---------------- fp32 -> bf16 convert (X then W) + colsum zeroing ----------------
__global__ __launch_bounds__(256) void cvt_zero_kernel(
    const float4* __restrict__ X, const float4* __restrict__ W,
    ushort4* __restrict__ dst, float* __restrict__ colsum) {
  int i = blockIdx.x * 256 + threadIdx.x;
  if (blockIdx.x < 32) colsum[i] = 0.f;          // zero colsum[8192]
  float4 v = (i < NX4) ? X[i] : W[i - NX4];
  ushort4 o;
  o.x = f2bf(v.x); o.y = f2bf(v.y); o.z = f2bf(v.z); o.w = f2bf(v.w);
  dst[i] = o;
}

// ---------------- GEMM: Q,K = X W^T + bias, stored as fp8 e4m3 (unscaled) ----------------
__global__ __launch_bounds__(256) void gemm_qk(
    const unsigned short* __restrict__ Xb,   // [8192][1024] bf16
    const unsigned short* __restrict__ Wb,   // [2048][1024] bf16
    const float* __restrict__ bias,          // [3072]
    unsigned char* __restrict__ C)           // [8192][2048] fp8 e4m3
{
  __shared__ unsigned short As[128 * 32];  // 8KB
  __shared__ unsigned short Bs[128 * 32];  // 8KB
  int t = threadIdx.x;
  int w = t >> 6, lane = t & 63;
  int l15 = lane & 15, lg = lane >> 4;
  int bid = blockIdx.x;
  int k2 = bid >> 3, xcd = bid & 7;
  int m0 = (xcd * 8 + (k2 >> 4)) * 128;
  int n0 = (k2 & 15) * 128;
  int wm = (w >> 1) * 64, wn = (w & 1) * 64;
  f32x4 acc[4][4] = {};

  for (int kt = 0; kt < D_MODEL / 32; ++kt) {
#pragma unroll
    for (int i = 0; i < 2; ++i) {
      int ob = w * 1024 + i * 4096;
      int o = ob + lane * 16;
      int row = o >> 6;
      int kb = (o & 63) ^ (((row >> 1) & 3) << 4);
      gl_lds16(Xb + (m0 + row) * D_MODEL + kt * 32 + (kb >> 1), (char*)As + ob);
      gl_lds16(Wb + (n0 + row) * D_MODEL + kt * 32 + (kb >> 1), (char*)Bs + ob);
    }
    __syncthreads();
    bf16x8 a[4], b[4];
#pragma unroll
    for (int mi = 0; mi < 4; mi++) {
      int row = wm + mi * 16 + l15;
      int kb = (lg * 16) ^ (((row >> 1) & 3) << 4);
      a[mi] = *(const bf16x8*)((const char*)As + row * 64 + kb);
    }
#pragma unroll
    for (int ni = 0; ni < 4; ni++) {
      int row = wn + ni * 16 + l15;
      int kb = (lg * 16) ^ (((row >> 1) & 3) << 4);
      b[ni] = *(const bf16x8*)((const char*)Bs + row * 64 + kb);
    }
#pragma unroll
    for (int mi = 0; mi < 4; mi++)
#pragma unroll
      for (int ni = 0; ni < 4; ni++)
        acc[mi][ni] = __builtin_amdgcn_mfma_f32_16x16x32_bf16(a[mi], b[ni], acc[mi][ni], 0, 0, 0);
    __syncthreads();
  }

#pragma unroll
  for (int ni = 0; ni < 4; ni++) {
    int n = n0 + wn + ni * 16 + l15;
    float bv = bias[n];
#pragma unroll
    for (int mi = 0; mi < 4; mi++) {
      int mbase = m0 + wm + mi * 16 + lg * 4;
#pragma unroll
      for (int r = 0; r < 4; r++) {
        float v = acc[mi][ni][r] + bv;
        unsigned u = __builtin_amdgcn_cvt_pk_fp8_f32(v, v, 0, false);
        C[(size_t)(mbase + r) * NQK + n] = (unsigned char)u;
      }
    }
  }
}

// ---------------- fused attention column sums (fp8, wave-private strips) ----------------
// wg = 512 threads (8 waves). All 8 waves share the same 32 q-rows of one (b,h); wave w
// owns key strip [w*256,(w+1)*256), staged 16-keys-at-a-time (4KB) into a wave-private
// double-buffered 2x4KB LDS slice. No barriers in the loop; counted vmcnt(4) pipelines.
// 512thr + 64KB LDS => 2 blocks/CU = 4 waves/EU = 128-VGPR budget: live set (~100) fits,
// no scratch spill (the round-6/7 failure mode).
__global__ __launch_bounds__(512, 4) void attn_fused(
    const unsigned char* __restrict__ C,   // [8192][2048] fp8
    float* __restrict__ colsum)            // [4][2048]
{
  __shared__ unsigned char Ks[65536];      // 8 waves x 2 bufs x 4KB
  int t = threadIdx.x;
  int w = t >> 6, lane = t & 63;
  int l15 = lane & 15, lg = lane >> 4;

  // XCD swizzle: 128 consecutive nids (2 bh) per XCD -> K slice (512KB fp8) L2-resident
  int nid = (blockIdx.x & 7) * 128 + (blockIdx.x >> 3);
  int bh = nid >> 6, rb = nid & 63;
  int b = bh >> 2, h = bh & 3;

  const unsigned char* Qbase = C + (size_t)(b * LSEQ + rb * 32) * NQK + h * 256;
  const unsigned char* Kbase = C + (size_t)(b * LSEQ + w * 256) * NQK + 1024 + h * 256;
  unsigned char* buf0 = Ks + w * 8192;
  unsigned char* buf1 = buf0 + 4096;

  // Q fragments: 32 rows x 256 hd fp8 (A-operand layout), 32 VGPRs
  long qf[2][8];
#pragma unroll
  for (int mi = 0; mi < 2; mi++)
#pragma unroll
    for (int kk = 0; kk < 8; kk++)
      qf[mi][kk] = *(const long*)(Qbase + (size_t)(mi * 16 + l15) * NQK + kk * 32 + lg * 8);
  asm volatile("s_waitcnt vmcnt(0)" ::: "memory");   // drain Q so vmcnt counts are exact
  __builtin_amdgcn_sched_barrier(0);

  float zacc[2][4] = {};
  unsigned E[16][2];                       // exp(S) packed 4x e4m3 per u32
  int swz = (l15 & 7) << 4;

  // stage tile nn (16 keys x 256B = 4KB) into dst, XOR-swizzled via source
#define STAGE(nn, dst)                                                         \
  {                                                                            \
    _Pragma("unroll")                                                          \
    for (int i = 0; i < 4; i++) {                                              \
      int o = i * 1024 + lane * 16;                                            \
      int s = o >> 8;                                                          \
      int db = (o & 255) ^ ((s & 7) << 4);                                     \
      gl_lds16(Kbase + (size_t)((nn) * 16 + s) * NQK + db, (dst) + o);         \
    }                                                                          \
  }

  STAGE(0, buf0);

#pragma unroll
  for (int n = 0; n < 16; n++) {
    unsigned char* cur = (n & 1) ? buf1 : buf0;
    unsigned char* nxt = (n & 1) ? buf0 : buf1;
    if (n < 15) {
      STAGE(n + 1, nxt);
      asm volatile("s_waitcnt vmcnt(4)" ::: "memory");  // tile n's 4 loads landed
    } else {
      asm volatile("s_waitcnt vmcnt(0)" ::: "memory");
    }
    __builtin_amdgcn_sched_barrier(0);

    f32x4 acc0 = {}, acc1 = {};
#pragma unroll
    for (int kk = 0; kk < 8; kk++) {
      long kf = *(const long*)(cur + l15 * 256 + ((kk * 32 + lg * 8) ^ swz));
      acc0 = __builtin_amdgcn_mfma_f32_16x16x32_fp8_fp8(qf[0][kk], kf, acc0, 0, 0, 0);
      acc1 = __builtin_amdgcn_mfma_f32_16x16x32_fp8_fp8(qf[1][kk], kf, acc1, 0, 0, 0);
    }
    {
      float e0 = __expf(acc0[0] * 0.0625f), e1 = __expf(acc0[1] * 0.0625f);
      float e2 = __expf(acc0[2] * 0.0625f), e3 = __expf(acc0[3] * 0.0625f);
      zacc[0][0] += e0; zacc[0][1] += e1; zacc[0][2] += e2; zacc[0][3] += e3;
      unsigned u = __builtin_amdgcn_cvt_pk_fp8_f32(e0, e1, 0, false);
      E[n][0] = __builtin_amdgcn_cvt_pk_fp8_f32(e2, e3, (int)u, true);
    }
    {
      float e0 = __expf(acc1[0] * 0.0625f), e1 = __expf(acc1[1] * 0.0625f);
      float e2 = __expf(acc1[2] * 0.0625f), e3 = __expf(acc1[3] * 0.0625f);
      zacc[1][0] += e0; zacc[1][1] += e1; zacc[1][2] += e2; zacc[1][3] += e3;
      unsigned u = __builtin_amdgcn_cvt_pk_fp8_f32(e0, e1, 0, false);
      E[n][1] = __builtin_amdgcn_cvt_pk_fp8_f32(e2, e3, (int)u, true);
    }
  }
#undef STAGE

  // ---- Z combine across the 8 key-strip waves ----
  __syncthreads();
  float* Zpf = (float*)Ks;                 // [8][32]
#pragma unroll
  for (int mi = 0; mi < 2; mi++)
#pragma unroll
    for (int r = 0; r < 4; r++) {
      float z = zacc[mi][r];
      z += __shfl_xor(z, 1, 64);
      z += __shfl_xor(z, 2, 64);
      z += __shfl_xor(z, 4, 64);
      z += __shfl_xor(z, 8, 64);
      if (l15 == 0) Zpf[w * 32 + mi * 16 + lg * 4 + r] = z;
    }
  __syncthreads();

  float invz[2][4];
#pragma unroll
  for (int mi = 0; mi < 2; mi++) {
    f32x4 s = {};
#pragma unroll
    for (int j = 0; j < 8; j++) {
      f32x4 p = *(const f32x4*)(Zpf + j * 32 + mi * 16 + lg * 4);
      s += p;
    }
    invz[mi][0] = 1.0f / s[0]; invz[mi][1] = 1.0f / s[1];
    invz[mi][2] = 1.0f / s[2]; invz[mi][3] = 1.0f / s[3];
  }

  // ---- column sums straight from register-resident fp8 E ----
#pragma unroll
  for (int n = 0; n < 16; n++) {
    float c = 0.f;
#pragma unroll
    for (int mi = 0; mi < 2; mi++) {
      c += __builtin_amdgcn_cvt_f32_fp8(E[n][mi], 0) * invz[mi][0];
      c += __builtin_amdgcn_cvt_f32_fp8(E[n][mi], 1) * invz[mi][1];
      c += __builtin_amdgcn_cvt_f32_fp8(E[n][mi], 2) * invz[mi][2];
      c += __builtin_amdgcn_cvt_f32_fp8(E[n][mi], 3) * invz[mi][3];
    }
    c += __shfl_xor(c, 16, 64);
    c += __shfl_xor(c, 32, 64);
    if (lane < 16)
      atomicAdd(&colsum[b * LSEQ + w * 256 + n * 16 + l15], c);
  }
}

// ---------------- finalize ----------------
__global__ __launch_bounds__(256) void finalize_kernel(
    const float* __restrict__ colsum, float* __restrict__ out) {
  __shared__ float red[256];
  int t = threadIdx.x;
  float acc = 0.f;
  for (int i = t; i < NB * LSEQ; i += 256) {
    float aw = colsum[i] * (1.0f / 8192.0f) + 1e-8f;
    acc += -aw * __logf(aw);
  }
  red[t] = acc;
  __syncthreads();
  for (int s = 128; s > 0; s >>= 1) {
    if (t < s) red[t] += red[t + s];
    __syncthreads();
  }
  if (t == 0) {
    float me = red[0] * 0.25f;
    out[0] = 1.0f / (1.0f + __expf(-me));
  }
}

extern "C" void kernel_launch(void* const* d_in, const int* in_sizes, int n_in,
                              void* d_out, int out_size, void* d_ws, size_t ws_size,
                              hipStream_t stream) {
  const float* hs   = (const float*)d_in[0];   // [4,2048,1024]
  const float* wgt  = (const float*)d_in[1];   // [3072,1024]
  const float* bias = (const float*)d_in[2];   // [3072]
  float* out = (float*)d_out;
  char* ws = (char*)d_ws;

  unsigned short* Xb = (unsigned short*)(ws);                   // 16 MB
  unsigned short* Wb = (unsigned short*)(ws + (16u << 20));     // 4 MB
  unsigned char*  C8 = (unsigned char*)(ws + (20u << 20));      // 16 MB fp8
  float* colsum = (float*)(ws + (36u << 20));                   // 32 KB

  cvt_zero_kernel<<<(NX4 + NW4) / 256, 256, 0, stream>>>(
      (const float4*)hs, (const float4*)wgt, (ushort4*)Xb, colsum);

  gemm_qk<<<1024, 256, 0, stream>>>(Xb, Wb, bias, C8);

  attn_fused<<<1024, 512, 0, stream>>>(C8, colsum);
  finalize_kernel<<<1, 256, 0, stream>>>(colsum, out);
}

// Round 9
// 154.257 us; speedup vs baseline: 1.0412x; 1.0148x over previous
//
#include <hip/hip_runtime.h>

typedef __attribute__((ext_vector_type(4))) float f32x4;
typedef __attribute__((ext_vector_type(8))) short bf16x8;

#define D_MODEL 1024
#define NQK     2048
#define LSEQ    2048
#define NB      4
#define NX4     2097152   // 8192*1024/4
#define NW4     524288    // 2048*1024/4

__device__ inline unsigned short f2bf(float f) {
  unsigned u = __float_as_uint(f);
  unsigned r = (u + 0x7FFFu + ((u >> 16) & 1u)) >> 16;
  return (unsigned short)r;
}

__device__ inline void gl_lds16(const void* g, void* l) {
  __builtin_amdgcn_global_load_lds((const __attribute__((address_space(1))) void*)g,
                                   (__attribute__((address_space(3))) void*)l, 16, 0, 0);
}

// ---------------- fp32 -> bf16 convert (X then W) + colsum zeroing ----------------
__global__ __launch_bounds__(256) void cvt_zero_kernel(
    const float4* __restrict__ X, const float4* __restrict__ W,
    ushort4* __restrict__ dst, float* __restrict__ colsum) {
  int i = blockIdx.x * 256 + threadIdx.x;
  if (blockIdx.x < 32) colsum[i] = 0.f;          // zero colsum[8192]
  float4 v = (i < NX4) ? X[i] : W[i - NX4];
  ushort4 o;
  o.x = f2bf(v.x); o.y = f2bf(v.y); o.z = f2bf(v.z); o.w = f2bf(v.w);
  dst[i] = o;
}

// ---------------- GEMM: Q,K = X W^T + bias, stored as fp8 e4m3 (unscaled) ----------------
__global__ __launch_bounds__(256) void gemm_qk(
    const unsigned short* __restrict__ Xb,   // [8192][1024] bf16
    const unsigned short* __restrict__ Wb,   // [2048][1024] bf16
    const float* __restrict__ bias,          // [3072]
    unsigned char* __restrict__ C)           // [8192][2048] fp8 e4m3
{
  __shared__ unsigned short As[128 * 32];  // 8KB
  __shared__ unsigned short Bs[128 * 32];  // 8KB
  int t = threadIdx.x;
  int w = t >> 6, lane = t & 63;
  int l15 = lane & 15, lg = lane >> 4;
  int bid = blockIdx.x;
  int k2 = bid >> 3, xcd = bid & 7;
  int m0 = (xcd * 8 + (k2 >> 4)) * 128;
  int n0 = (k2 & 15) * 128;
  int wm = (w >> 1) * 64, wn = (w & 1) * 64;
  f32x4 acc[4][4] = {};

  for (int kt = 0; kt < D_MODEL / 32; ++kt) {
#pragma unroll
    for (int i = 0; i < 2; ++i) {
      int ob = w * 1024 + i * 4096;
      int o = ob + lane * 16;
      int row = o >> 6;
      int kb = (o & 63) ^ (((row >> 1) & 3) << 4);
      gl_lds16(Xb + (m0 + row) * D_MODEL + kt * 32 + (kb >> 1), (char*)As + ob);
      gl_lds16(Wb + (n0 + row) * D_MODEL + kt * 32 + (kb >> 1), (char*)Bs + ob);
    }
    __syncthreads();
    bf16x8 a[4], b[4];
#pragma unroll
    for (int mi = 0; mi < 4; mi++) {
      int row = wm + mi * 16 + l15;
      int kb = (lg * 16) ^ (((row >> 1) & 3) << 4);
      a[mi] = *(const bf16x8*)((const char*)As + row * 64 + kb);
    }
#pragma unroll
    for (int ni = 0; ni < 4; ni++) {
      int row = wn + ni * 16 + l15;
      int kb = (lg * 16) ^ (((row >> 1) & 3) << 4);
      b[ni] = *(const bf16x8*)((const char*)Bs + row * 64 + kb);
    }
#pragma unroll
    for (int mi = 0; mi < 4; mi++)
#pragma unroll
      for (int ni = 0; ni < 4; ni++)
        acc[mi][ni] = __builtin_amdgcn_mfma_f32_16x16x32_bf16(a[mi], b[ni], acc[mi][ni], 0, 0, 0);
    __syncthreads();
  }

#pragma unroll
  for (int ni = 0; ni < 4; ni++) {
    int n = n0 + wn + ni * 16 + l15;
    float bv = bias[n];
#pragma unroll
    for (int mi = 0; mi < 4; mi++) {
      int mbase = m0 + wm + mi * 16 + lg * 4;
#pragma unroll
      for (int r = 0; r < 4; r++) {
        float v = acc[mi][ni][r] + bv;
        unsigned u = __builtin_amdgcn_cvt_pk_fp8_f32(v, v, 0, false);
        C[(size_t)(mbase + r) * NQK + n] = (unsigned char)u;
      }
    }
  }
}

// ---------------- fused attention column sums (fp8, wave-private strips) ----------------
// wg = 512 threads (8 waves), all sharing 32 q-rows of one (b,h); wave w owns key strip
// [w*256,(w+1)*256), staged 16-keys (4KB) at a time into a wave-private double-buffered
// 2x4KB LDS slice. FULLY MANUALLY UNROLLED 16-tile pipeline with NAMED E registers —
// no arrays that can be demoted to scratch (the round-6..8 spill bug, rule #20).
__global__ __attribute__((amdgpu_flat_work_group_size(512, 512),
                          amdgpu_waves_per_eu(4, 4))) void attn_fused(
    const unsigned char* __restrict__ C,   // [8192][2048] fp8
    float* __restrict__ colsum)            // [4][2048]
{
  __shared__ unsigned char Ks[65536];      // 8 waves x 2 bufs x 4KB
  int t = threadIdx.x;
  int w = t >> 6, lane = t & 63;
  int l15 = lane & 15, lg = lane >> 4;

  // XCD swizzle: 128 consecutive nids (2 bh) per XCD -> K slice L2-resident
  int nid = (blockIdx.x & 7) * 128 + (blockIdx.x >> 3);
  int bh = nid >> 6, rb = nid & 63;
  int b = bh >> 2, h = bh & 3;

  const unsigned char* Qbase = C + (size_t)(b * LSEQ + rb * 32) * NQK + h * 256;
  const unsigned char* Kbase = C + (size_t)(b * LSEQ + w * 256) * NQK + 1024 + h * 256;
  unsigned char* buf0 = Ks + w * 8192;
  unsigned char* buf1 = buf0 + 4096;

  // Q fragments: 32 rows x 256 hd fp8 (A-operand layout), 32 VGPRs
  long qf0[8], qf1[8];
#pragma unroll
  for (int kk = 0; kk < 8; kk++) {
    qf0[kk] = *(const long*)(Qbase + (size_t)(l15) * NQK + kk * 32 + lg * 8);
    qf1[kk] = *(const long*)(Qbase + (size_t)(16 + l15) * NQK + kk * 32 + lg * 8);
  }
  asm volatile("s_waitcnt vmcnt(0)" ::: "memory");   // drain Q so vmcnt counts are exact
  __builtin_amdgcn_sched_barrier(0);

  float z00 = 0.f, z01 = 0.f, z02 = 0.f, z03 = 0.f;
  float z10 = 0.f, z11 = 0.f, z12 = 0.f, z13 = 0.f;
  unsigned E0a, E1a, E2a, E3a, E4a, E5a, E6a, E7a;
  unsigned E8a, E9a, E10a, E11a, E12a, E13a, E14a, E15a;
  unsigned E0b, E1b, E2b, E3b, E4b, E5b, E6b, E7b;
  unsigned E8b, E9b, E10b, E11b, E12b, E13b, E14b, E15b;
  int swz = (l15 & 7) << 4;

  // stage tile nn (16 keys x 256B = 4KB) into dst, XOR-swizzled via source
#define STAGE(nn, dst)                                                         \
  {                                                                            \
    _Pragma("unroll")                                                          \
    for (int i = 0; i < 4; i++) {                                              \
      int o = i * 1024 + lane * 16;                                            \
      int s = o >> 8;                                                          \
      int db = (o & 255) ^ ((s & 7) << 4);                                     \
      gl_lds16(Kbase + (size_t)((nn) * 16 + s) * NQK + db, (dst) + o);         \
    }                                                                          \
  }

#define TILE(n, cur, nxt, STG)                                                 \
  {                                                                            \
    if (STG) {                                                                 \
      STAGE((n) + 1, nxt);                                                     \
      asm volatile("s_waitcnt vmcnt(4)" ::: "memory");                         \
    } else {                                                                   \
      asm volatile("s_waitcnt vmcnt(0)" ::: "memory");                         \
    }                                                                          \
    __builtin_amdgcn_sched_barrier(0);                                         \
    f32x4 acc0 = {}, acc1 = {};                                                \
    _Pragma("unroll")                                                          \
    for (int kk = 0; kk < 8; kk++) {                                           \
      long kf = *(const long*)((cur) + l15 * 256 + ((kk * 32 + lg * 8) ^ swz));\
      acc0 = __builtin_amdgcn_mfma_f32_16x16x32_fp8_fp8(qf0[kk], kf, acc0, 0, 0, 0); \
      acc1 = __builtin_amdgcn_mfma_f32_16x16x32_fp8_fp8(qf1[kk], kf, acc1, 0, 0, 0); \
    }                                                                          \
    float e0 = __expf(acc0[0] * 0.0625f), e1 = __expf(acc0[1] * 0.0625f);      \
    float e2 = __expf(acc0[2] * 0.0625f), e3 = __expf(acc0[3] * 0.0625f);      \
    z00 += e0; z01 += e1; z02 += e2; z03 += e3;                                \
    unsigned ua = __builtin_amdgcn_cvt_pk_fp8_f32(e0, e1, 0, false);           \
    E##n##a = __builtin_amdgcn_cvt_pk_fp8_f32(e2, e3, (int)ua, true);          \
    float f0 = __expf(acc1[0] * 0.0625f), f1 = __expf(acc1[1] * 0.0625f);      \
    float f2 = __expf(acc1[2] * 0.0625f), f3 = __expf(acc1[3] * 0.0625f);      \
    z10 += f0; z11 += f1; z12 += f2; z13 += f3;                                \
    unsigned ub = __builtin_amdgcn_cvt_pk_fp8_f32(f0, f1, 0, false);           \
    E##n##b = __builtin_amdgcn_cvt_pk_fp8_f32(f2, f3, (int)ub, true);          \
  }

  STAGE(0, buf0);
  TILE(0,  buf0, buf1, 1)
  TILE(1,  buf1, buf0, 1)
  TILE(2,  buf0, buf1, 1)
  TILE(3,  buf1, buf0, 1)
  TILE(4,  buf0, buf1, 1)
  TILE(5,  buf1, buf0, 1)
  TILE(6,  buf0, buf1, 1)
  TILE(7,  buf1, buf0, 1)
  TILE(8,  buf0, buf1, 1)
  TILE(9,  buf1, buf0, 1)
  TILE(10, buf0, buf1, 1)
  TILE(11, buf1, buf0, 1)
  TILE(12, buf0, buf1, 1)
  TILE(13, buf1, buf0, 1)
  TILE(14, buf0, buf1, 1)
  TILE(15, buf1, buf0, 0)
#undef TILE
#undef STAGE

  // ---- Z combine across the 8 key-strip waves ----
  __syncthreads();
  float* Zpf = (float*)Ks;                 // [8][32]
#define REDZ(zv, slot)                                                         \
  {                                                                            \
    float z = (zv);                                                            \
    z += __shfl_xor(z, 1, 64);                                                 \
    z += __shfl_xor(z, 2, 64);                                                 \
    z += __shfl_xor(z, 4, 64);                                                 \
    z += __shfl_xor(z, 8, 64);                                                 \
    if (l15 == 0) Zpf[w * 32 + (slot)] = z;                                    \
  }
  REDZ(z00, lg * 4 + 0)  REDZ(z01, lg * 4 + 1)
  REDZ(z02, lg * 4 + 2)  REDZ(z03, lg * 4 + 3)
  REDZ(z10, 16 + lg * 4 + 0)  REDZ(z11, 16 + lg * 4 + 1)
  REDZ(z12, 16 + lg * 4 + 2)  REDZ(z13, 16 + lg * 4 + 3)
#undef REDZ
  __syncthreads();

  float invz00, invz01, invz02, invz03, invz10, invz11, invz12, invz13;
  {
    f32x4 s0 = {}, s1 = {};
#pragma unroll
    for (int j = 0; j < 8; j++) {
      s0 += *(const f32x4*)(Zpf + j * 32 + lg * 4);
      s1 += *(const f32x4*)(Zpf + j * 32 + 16 + lg * 4);
    }
    invz00 = 1.0f / s0[0]; invz01 = 1.0f / s0[1];
    invz02 = 1.0f / s0[2]; invz03 = 1.0f / s0[3];
    invz10 = 1.0f / s1[0]; invz11 = 1.0f / s1[1];
    invz12 = 1.0f / s1[2]; invz13 = 1.0f / s1[3];
  }

  // ---- column sums straight from register-resident fp8 E ----
#define COL(n)                                                                 \
  {                                                                            \
    float c = 0.f;                                                             \
    c += __builtin_amdgcn_cvt_f32_fp8(E##n##a, 0) * invz00;                    \
    c += __builtin_amdgcn_cvt_f32_fp8(E##n##a, 1) * invz01;                    \
    c += __builtin_amdgcn_cvt_f32_fp8(E##n##a, 2) * invz02;                    \
    c += __builtin_amdgcn_cvt_f32_fp8(E##n##a, 3) * invz03;                    \
    c += __builtin_amdgcn_cvt_f32_fp8(E##n##b, 0) * invz10;                    \
    c += __builtin_amdgcn_cvt_f32_fp8(E##n##b, 1) * invz11;                    \
    c += __builtin_amdgcn_cvt_f32_fp8(E##n##b, 2) * invz12;                    \
    c += __builtin_amdgcn_cvt_f32_fp8(E##n##b, 3) * invz13;                    \
    c += __shfl_xor(c, 16, 64);                                                \
    c += __shfl_xor(c, 32, 64);                                                \
    if (lane < 16)                                                             \
      atomicAdd(&colsum[b * LSEQ + w * 256 + (n) * 16 + l15], c);              \
  }
  COL(0)  COL(1)  COL(2)  COL(3)  COL(4)  COL(5)  COL(6)  COL(7)
  COL(8)  COL(9)  COL(10) COL(11) COL(12) COL(13) COL(14) COL(15)
#undef COL
}

// ---------------- finalize ----------------
__global__ __launch_bounds__(256) void finalize_kernel(
    const float* __restrict__ colsum, float* __restrict__ out) {
  __shared__ float red[256];
  int t = threadIdx.x;
  float acc = 0.f;
  for (int i = t; i < NB * LSEQ; i += 256) {
    float aw = colsum[i] * (1.0f / 8192.0f) + 1e-8f;
    acc += -aw * __logf(aw);
  }
  red[t] = acc;
  __syncthreads();
  for (int s = 128; s > 0; s >>= 1) {
    if (t < s) red[t] += red[t + s];
    __syncthreads();
  }
  if (t == 0) {
    float me = red[0] * 0.25f;
    out[0] = 1.0f / (1.0f + __expf(-me));
  }
}

extern "C" void kernel_launch(void* const* d_in, const int* in_sizes, int n_in,
                              void* d_out, int out_size, void* d_ws, size_t ws_size,
                              hipStream_t stream) {
  const float* hs   = (const float*)d_in[0];   // [4,2048,1024]
  const float* wgt  = (const float*)d_in[1];   // [3072,1024]
  const float* bias = (const float*)d_in[2];   // [3072]
  float* out = (float*)d_out;
  char* ws = (char*)d_ws;

  unsigned short* Xb = (unsigned short*)(ws);                   // 16 MB
  unsigned short* Wb = (unsigned short*)(ws + (16u << 20));     // 4 MB
  unsigned char*  C8 = (unsigned char*)(ws + (20u << 20));      // 16 MB fp8
  float* colsum = (float*)(ws + (36u << 20));                   // 32 KB

  cvt_zero_kernel<<<(NX4 + NW4) / 256, 256, 0, stream>>>(
      (const float4*)hs, (const float4*)wgt, (ushort4*)Xb, colsum);

  gemm_qk<<<1024, 256, 0, stream>>>(Xb, Wb, bias, C8);

  attn_fused<<<1024, 512, 0, stream>>>(C8, colsum);
  finalize_kernel<<<1, 256, 0, stream>>>(colsum, out);
}

// Round 10
// 137.668 us; speedup vs baseline: 1.1666x; 1.1205x over previous
//
#include <hip/hip_runtime.h>

typedef __attribute__((ext_vector_type(4))) float f32x4;
typedef __attribute__((ext_vector_type(8))) short bf16x8;

#define D_MODEL 1024
#define NQK     2048
#define LSEQ    2048
#define NB      4
#define NX4     2097152   // 8192*1024/4
#define NW4     524288    // 2048*1024/4

__device__ inline unsigned short f2bf(float f) {
  unsigned u = __float_as_uint(f);
  unsigned r = (u + 0x7FFFu + ((u >> 16) & 1u)) >> 16;
  return (unsigned short)r;
}

__device__ inline void gl_lds16(const void* g, void* l) {
  __builtin_amdgcn_global_load_lds((const __attribute__((address_space(1))) void*)g,
                                   (__attribute__((address_space(3))) void*)l, 16, 0, 0);
}

// ---------------- fp32 -> bf16 convert (X then W) + colsum zeroing ----------------
__global__ __launch_bounds__(256) void cvt_zero_kernel(
    const float4* __restrict__ X, const float4* __restrict__ W,
    ushort4* __restrict__ dst, float* __restrict__ colsum) {
  int i = blockIdx.x * 256 + threadIdx.x;
  if (blockIdx.x < 32) colsum[i] = 0.f;          // zero colsum[8192]
  float4 v = (i < NX4) ? X[i] : W[i - NX4];
  ushort4 o;
  o.x = f2bf(v.x); o.y = f2bf(v.y); o.z = f2bf(v.z); o.w = f2bf(v.w);
  dst[i] = o;
}

// ---------------- GEMM: Q,K = X W^T + bias, stored as fp8 e4m3 (unscaled) ----------------
__global__ __launch_bounds__(256) void gemm_qk(
    const unsigned short* __restrict__ Xb,   // [8192][1024] bf16
    const unsigned short* __restrict__ Wb,   // [2048][1024] bf16
    const float* __restrict__ bias,          // [3072]
    unsigned char* __restrict__ C)           // [8192][2048] fp8 e4m3
{
  __shared__ unsigned short As[128 * 32];  // 8KB
  __shared__ unsigned short Bs[128 * 32];  // 8KB
  int t = threadIdx.x;
  int w = t >> 6, lane = t & 63;
  int l15 = lane & 15, lg = lane >> 4;
  int bid = blockIdx.x;
  int k2 = bid >> 3, xcd = bid & 7;
  int m0 = (xcd * 8 + (k2 >> 4)) * 128;
  int n0 = (k2 & 15) * 128;
  int wm = (w >> 1) * 64, wn = (w & 1) * 64;
  f32x4 acc[4][4] = {};

  for (int kt = 0; kt < D_MODEL / 32; ++kt) {
#pragma unroll
    for (int i = 0; i < 2; ++i) {
      int ob = w * 1024 + i * 4096;
      int o = ob + lane * 16;
      int row = o >> 6;
      int kb = (o & 63) ^ (((row >> 1) & 3) << 4);
      gl_lds16(Xb + (m0 + row) * D_MODEL + kt * 32 + (kb >> 1), (char*)As + ob);
      gl_lds16(Wb + (n0 + row) * D_MODEL + kt * 32 + (kb >> 1), (char*)Bs + ob);
    }
    __syncthreads();
    bf16x8 a[4], b[4];
#pragma unroll
    for (int mi = 0; mi < 4; mi++) {
      int row = wm + mi * 16 + l15;
      int kb = (lg * 16) ^ (((row >> 1) & 3) << 4);
      a[mi] = *(const bf16x8*)((const char*)As + row * 64 + kb);
    }
#pragma unroll
    for (int ni = 0; ni < 4; ni++) {
      int row = wn + ni * 16 + l15;
      int kb = (lg * 16) ^ (((row >> 1) & 3) << 4);
      b[ni] = *(const bf16x8*)((const char*)Bs + row * 64 + kb);
    }
#pragma unroll
    for (int mi = 0; mi < 4; mi++)
#pragma unroll
      for (int ni = 0; ni < 4; ni++)
        acc[mi][ni] = __builtin_amdgcn_mfma_f32_16x16x32_bf16(a[mi], b[ni], acc[mi][ni], 0, 0, 0);
    __syncthreads();
  }

#pragma unroll
  for (int ni = 0; ni < 4; ni++) {
    int n = n0 + wn + ni * 16 + l15;
    float bv = bias[n];
#pragma unroll
    for (int mi = 0; mi < 4; mi++) {
      int mbase = m0 + wm + mi * 16 + lg * 4;
#pragma unroll
      for (int r = 0; r < 4; r++) {
        float v = acc[mi][ni][r] + bv;
        unsigned u = __builtin_amdgcn_cvt_pk_fp8_f32(v, v, 0, false);
        C[(size_t)(mbase + r) * NQK + n] = (unsigned char)u;
      }
    }
  }
}

// ---------------- fused attention column sums (fp8, wave-private strips) ----------------
// wg = 512 threads (8 waves), all sharing 32 q-rows of one (b,h); wave w owns key strip
// [w*256,(w+1)*256), staged 32-keys (8KB) at a time into a wave-private double-buffered
// 2x8KB LDS slice (128KB total => 1 wg/CU => 2 waves/EU => 256-VGPR budget, the
// round-4/5 regalloc regime that measured VGPR=116/120 with zero spill).
// Plain __launch_bounds__(512): no waves/EU constraint (rounds 6-9's 64-VGPR trigger).
// Fully manually unrolled 8-tile pipeline, named E registers (rule #20), counted vmcnt(8).
__global__ __launch_bounds__(512) void attn_fused(
    const unsigned char* __restrict__ C,   // [8192][2048] fp8
    float* __restrict__ colsum)            // [4][2048]
{
  __shared__ unsigned char Ks[131072];     // 8 waves x 2 bufs x 8KB
  int t = threadIdx.x;
  int w = t >> 6, lane = t & 63;
  int l15 = lane & 15, lg = lane >> 4;

  // XCD swizzle: 128 consecutive nids (2 bh) per XCD -> K slice L2-resident
  int nid = (blockIdx.x & 7) * 128 + (blockIdx.x >> 3);
  int bh = nid >> 6, rb = nid & 63;
  int b = bh >> 2, h = bh & 3;

  const unsigned char* Qbase = C + (size_t)(b * LSEQ + rb * 32) * NQK + h * 256;
  const unsigned char* Kbase = C + (size_t)(b * LSEQ + w * 256) * NQK + 1024 + h * 256;
  unsigned char* buf0 = Ks + w * 16384;
  unsigned char* buf1 = buf0 + 8192;

  // Q fragments: 32 rows x 256 hd fp8 (A-operand layout), 32 VGPRs
  long qf0[8], qf1[8];
#pragma unroll
  for (int kk = 0; kk < 8; kk++) {
    qf0[kk] = *(const long*)(Qbase + (size_t)(l15) * NQK + kk * 32 + lg * 8);
    qf1[kk] = *(const long*)(Qbase + (size_t)(16 + l15) * NQK + kk * 32 + lg * 8);
  }
  asm volatile("s_waitcnt vmcnt(0)" ::: "memory");   // drain Q so vmcnt counts are exact
  __builtin_amdgcn_sched_barrier(0);

  float z00 = 0.f, z01 = 0.f, z02 = 0.f, z03 = 0.f;
  float z10 = 0.f, z11 = 0.f, z12 = 0.f, z13 = 0.f;
  // E: exp(S) packed 4x e4m3 per u32; frag f (16 keys) x {a: rows m0, b: rows m1}
  unsigned E0a, E1a, E2a, E3a, E4a, E5a, E6a, E7a;
  unsigned E8a, E9a, E10a, E11a, E12a, E13a, E14a, E15a;
  unsigned E0b, E1b, E2b, E3b, E4b, E5b, E6b, E7b;
  unsigned E8b, E9b, E10b, E11b, E12b, E13b, E14b, E15b;
  int swz = (l15 & 7) << 4;

  // stage tile nn (32 keys x 256B = 8KB) into dst, XOR-swizzled via source
#define STAGE(nn, dst)                                                         \
  {                                                                            \
    _Pragma("unroll")                                                          \
    for (int i = 0; i < 8; i++) {                                              \
      int o = i * 1024 + lane * 16;                                            \
      int s = o >> 8;                                                          \
      int db = (o & 255) ^ ((s & 7) << 4);                                     \
      gl_lds16(Kbase + (size_t)((nn) * 32 + s) * NQK + db, (dst) + o);         \
    }                                                                          \
  }

#define PACK(acc, Z0, Z1, Z2, Z3, Edst)                                        \
  {                                                                            \
    float e0 = __expf((acc)[0] * 0.0625f), e1 = __expf((acc)[1] * 0.0625f);    \
    float e2 = __expf((acc)[2] * 0.0625f), e3 = __expf((acc)[3] * 0.0625f);    \
    Z0 += e0; Z1 += e1; Z2 += e2; Z3 += e3;                                    \
    unsigned u_ = __builtin_amdgcn_cvt_pk_fp8_f32(e0, e1, 0, false);           \
    Edst = __builtin_amdgcn_cvt_pk_fp8_f32(e2, e3, (int)u_, true);             \
  }

  // tile = 32 keys = 2 key-frags (g0: rows l15, g1: rows 16+l15)
#define TILE(n, EA0, EB0, EA1, EB1, cur, nxt, STG)                             \
  {                                                                            \
    if (STG) {                                                                 \
      STAGE((n) + 1, nxt);                                                     \
      asm volatile("s_waitcnt vmcnt(8)" ::: "memory");                         \
    } else {                                                                   \
      asm volatile("s_waitcnt vmcnt(0)" ::: "memory");                         \
    }                                                                          \
    __builtin_amdgcn_sched_barrier(0);                                         \
    f32x4 a00 = {}, a01 = {}, a10 = {}, a11 = {};                              \
    _Pragma("unroll")                                                          \
    for (int kk = 0; kk < 8; kk++) {                                           \
      int co = (kk * 32 + lg * 8) ^ swz;                                       \
      long kf0 = *(const long*)((cur) + l15 * 256 + co);                       \
      long kf1 = *(const long*)((cur) + (16 + l15) * 256 + co);                \
      a00 = __builtin_amdgcn_mfma_f32_16x16x32_fp8_fp8(qf0[kk], kf0, a00, 0, 0, 0); \
      a01 = __builtin_amdgcn_mfma_f32_16x16x32_fp8_fp8(qf1[kk], kf0, a01, 0, 0, 0); \
      a10 = __builtin_amdgcn_mfma_f32_16x16x32_fp8_fp8(qf0[kk], kf1, a10, 0, 0, 0); \
      a11 = __builtin_amdgcn_mfma_f32_16x16x32_fp8_fp8(qf1[kk], kf1, a11, 0, 0, 0); \
    }                                                                          \
    PACK(a00, z00, z01, z02, z03, EA0)                                         \
    PACK(a01, z10, z11, z12, z13, EB0)                                         \
    PACK(a10, z00, z01, z02, z03, EA1)                                         \
    PACK(a11, z10, z11, z12, z13, EB1)                                         \
  }

  STAGE(0, buf0);
  TILE(0, E0a,  E0b,  E1a,  E1b,  buf0, buf1, 1)
  TILE(1, E2a,  E2b,  E3a,  E3b,  buf1, buf0, 1)
  TILE(2, E4a,  E4b,  E5a,  E5b,  buf0, buf1, 1)
  TILE(3, E6a,  E6b,  E7a,  E7b,  buf1, buf0, 1)
  TILE(4, E8a,  E8b,  E9a,  E9b,  buf0, buf1, 1)
  TILE(5, E10a, E10b, E11a, E11b, buf1, buf0, 1)
  TILE(6, E12a, E12b, E13a, E13b, buf0, buf1, 1)
  TILE(7, E14a, E14b, E15a, E15b, buf1, buf0, 0)
#undef TILE
#undef PACK
#undef STAGE

  // ---- Z combine across the 8 key-strip waves ----
  __syncthreads();
  float* Zpf = (float*)Ks;                 // [8][32]
#define REDZ(zv, slot)                                                         \
  {                                                                            \
    float z = (zv);                                                            \
    z += __shfl_xor(z, 1, 64);                                                 \
    z += __shfl_xor(z, 2, 64);                                                 \
    z += __shfl_xor(z, 4, 64);                                                 \
    z += __shfl_xor(z, 8, 64);                                                 \
    if (l15 == 0) Zpf[w * 32 + (slot)] = z;                                    \
  }
  REDZ(z00, lg * 4 + 0)  REDZ(z01, lg * 4 + 1)
  REDZ(z02, lg * 4 + 2)  REDZ(z03, lg * 4 + 3)
  REDZ(z10, 16 + lg * 4 + 0)  REDZ(z11, 16 + lg * 4 + 1)
  REDZ(z12, 16 + lg * 4 + 2)  REDZ(z13, 16 + lg * 4 + 3)
#undef REDZ
  __syncthreads();

  float invz00, invz01, invz02, invz03, invz10, invz11, invz12, invz13;
  {
    f32x4 s0 = {}, s1 = {};
#pragma unroll
    for (int j = 0; j < 8; j++) {
      s0 += *(const f32x4*)(Zpf + j * 32 + lg * 4);
      s1 += *(const f32x4*)(Zpf + j * 32 + 16 + lg * 4);
    }
    invz00 = 1.0f / s0[0]; invz01 = 1.0f / s0[1];
    invz02 = 1.0f / s0[2]; invz03 = 1.0f / s0[3];
    invz10 = 1.0f / s1[0]; invz11 = 1.0f / s1[1];
    invz12 = 1.0f / s1[2]; invz13 = 1.0f / s1[3];
  }

  // ---- column sums straight from register-resident fp8 E ----
#define COL(f)                                                                 \
  {                                                                            \
    float c = 0.f;                                                             \
    c += __builtin_amdgcn_cvt_f32_fp8(E##f##a, 0) * invz00;                    \
    c += __builtin_amdgcn_cvt_f32_fp8(E##f##a, 1) * invz01;                    \
    c += __builtin_amdgcn_cvt_f32_fp8(E##f##a, 2) * invz02;                    \
    c += __builtin_amdgcn_cvt_f32_fp8(E##f##a, 3) * invz03;                    \
    c += __builtin_amdgcn_cvt_f32_fp8(E##f##b, 0) * invz10;                    \
    c += __builtin_amdgcn_cvt_f32_fp8(E##f##b, 1) * invz11;                    \
    c += __builtin_amdgcn_cvt_f32_fp8(E##f##b, 2) * invz12;                    \
    c += __builtin_amdgcn_cvt_f32_fp8(E##f##b, 3) * invz13;                    \
    c += __shfl_xor(c, 16, 64);                                                \
    c += __shfl_xor(c, 32, 64);                                                \
    if (lane < 16)                                                             \
      atomicAdd(&colsum[b * LSEQ + w * 256 + (f) * 16 + l15], c);              \
  }
  COL(0)  COL(1)  COL(2)  COL(3)  COL(4)  COL(5)  COL(6)  COL(7)
  COL(8)  COL(9)  COL(10) COL(11) COL(12) COL(13) COL(14) COL(15)
#undef COL
}

// ---------------- finalize ----------------
__global__ __launch_bounds__(256) void finalize_kernel(
    const float* __restrict__ colsum, float* __restrict__ out) {
  __shared__ float red[256];
  int t = threadIdx.x;
  float acc = 0.f;
  for (int i = t; i < NB * LSEQ; i += 256) {
    float aw = colsum[i] * (1.0f / 8192.0f) + 1e-8f;
    acc += -aw * __logf(aw);
  }
  red[t] = acc;
  __syncthreads();
  for (int s = 128; s > 0; s >>= 1) {
    if (t < s) red[t] += red[t + s];
    __syncthreads();
  }
  if (t == 0) {
    float me = red[0] * 0.25f;
    out[0] = 1.0f / (1.0f + __expf(-me));
  }
}

extern "C" void kernel_launch(void* const* d_in, const int* in_sizes, int n_in,
                              void* d_out, int out_size, void* d_ws, size_t ws_size,
                              hipStream_t stream) {
  const float* hs   = (const float*)d_in[0];   // [4,2048,1024]
  const float* wgt  = (const float*)d_in[1];   // [3072,1024]
  const float* bias = (const float*)d_in[2];   // [3072]
  float* out = (float*)d_out;
  char* ws = (char*)d_ws;

  unsigned short* Xb = (unsigned short*)(ws);                   // 16 MB
  unsigned short* Wb = (unsigned short*)(ws + (16u << 20));     // 4 MB
  unsigned char*  C8 = (unsigned char*)(ws + (20u << 20));      // 16 MB fp8
  float* colsum = (float*)(ws + (36u << 20));                   // 32 KB

  cvt_zero_kernel<<<(NX4 + NW4) / 256, 256, 0, stream>>>(
      (const float4*)hs, (const float4*)wgt, (ushort4*)Xb, colsum);

  gemm_qk<<<1024, 256, 0, stream>>>(Xb, Wb, bias, C8);

  attn_fused<<<1024, 512, 0, stream>>>(C8, colsum);
  finalize_kernel<<<1, 256, 0, stream>>>(colsum, out);
}